// Round 1
// baseline (1076.545 us; speedup 1.0000x reference)
//
#include <hip/hip_runtime.h>
#include <hip/hip_bf16.h>

// Problem constants
#define B_   8
#define S_   512
#define N_   1024
#define F_   32
#define H_   64
#define G0_  32
#define T_   15          // trailing time steps needed (receptive field of last pos)
#define BT_  (B_ * T_)   // 120
#define C1_  (BT_ * G0_) // 3840 columns for the big GEMMs

// ---------------------------------------------------------------------------
// Kernel: row degree -> dis[r] = rsqrt(deg), deg = sum_n adj[r,n] + 1 (self loop)
// ---------------------------------------------------------------------------
__global__ void k_deg(const float* __restrict__ adj, float* __restrict__ dis) {
    int r = blockIdx.x;
    int tid = threadIdx.x;
    const float* row = adj + (size_t)r * N_;
    float p = 0.f;
    for (int n = tid; n < N_; n += 256) p += row[n];
    __shared__ float red[256];
    red[tid] = p;
    __syncthreads();
    for (int s = 128; s > 0; s >>= 1) {
        if (tid < s) red[tid] += red[tid + s];
        __syncthreads();
    }
    if (tid == 0) {
        float deg = red[0] + 1.0f;
        dis[r] = (deg > 0.f) ? rsqrtf(deg) : 0.f;
    }
}

// ---------------------------------------------------------------------------
// Kernel: AN[m,n] = dis[m] * (adj[m,n] + (m==n)) * dis[n]
// ---------------------------------------------------------------------------
__global__ void k_an(const float* __restrict__ adj, const float* __restrict__ dis,
                     float* __restrict__ an) {
    int idx = blockIdx.x * 256 + threadIdx.x;   // grid 4096 x 256 == N_*N_
    int m = idx >> 10, n = idx & 1023;
    float v = adj[idx] + (m == n ? 1.0f : 0.0f);
    an[idx] = dis[m] * v * dis[n];
}

// ---------------------------------------------------------------------------
// Kernel: XW0[n, bt*32+g] = x[b, s(tau), n, :] @ w0     (no bias here)
// grid (128, 120), block 256 = 8 n-rows x 32 g
// ---------------------------------------------------------------------------
__global__ void k_xw0(const float* __restrict__ x, const float* __restrict__ w0,
                      float* __restrict__ xw0) {
    int bt = blockIdx.y;
    int n0 = blockIdx.x * 8;
    int b = bt / T_, tau = bt % T_;
    int s = S_ - T_ + tau;
    __shared__ float w0s[F_ * G0_];   // 1024
    __shared__ float xs[8][F_];
    int tid = threadIdx.x;
    *(float4*)&w0s[tid * 4] = *(const float4*)&w0[tid * 4];
    {
        int nl = tid >> 5, f = tid & 31;
        xs[nl][f] = x[(((size_t)(b * S_ + s)) * N_ + (n0 + nl)) * F_ + f];
    }
    __syncthreads();
    int nl = tid >> 5, g = tid & 31;
    float acc = 0.f;
#pragma unroll
    for (int f = 0; f < F_; ++f) acc += xs[nl][f] * w0s[f * G0_ + g];
    xw0[(size_t)(n0 + nl) * C1_ + bt * G0_ + g] = acc;
}

// ---------------------------------------------------------------------------
// Kernel: Y = AN(1024x1024) @ X(1024xC1_), optional epilogue relu(. + bias[col%32])
// Block tile 128(M) x 64(N), BK=16, 256 threads, per-thread 8x4.
// grid (C1_/64=60, 1024/128=8)
// ---------------------------------------------------------------------------
__global__ __launch_bounds__(256) void k_gemm(const float* __restrict__ A,
                                              const float* __restrict__ X,
                                              float* __restrict__ Y,
                                              const float* __restrict__ bias,
                                              int relu) {
    __shared__ float As[16 * 132];   // [k][m], padded to 132 to break bank conflicts
    __shared__ float Xs[16 * 64];    // [k][c]
    int tid = threadIdx.x;
    int tx = tid & 15, ty = tid >> 4;
    int rb = blockIdx.y * 128, cb = blockIdx.x * 64;

    float acc[8][4];
#pragma unroll
    for (int r = 0; r < 8; ++r)
#pragma unroll
        for (int c = 0; c < 4; ++c) acc[r][c] = 0.f;

    int am = tid >> 1, ak = (tid & 1) * 8;   // A-tile: 128 rows x 16 k
    int xk = tid >> 4, xc = (tid & 15) * 4;  // X-tile: 16 k x 64 c

    for (int k0 = 0; k0 < 1024; k0 += 16) {
        float4 a0 = *(const float4*)&A[(size_t)(rb + am) * 1024 + k0 + ak];
        float4 a1 = *(const float4*)&A[(size_t)(rb + am) * 1024 + k0 + ak + 4];
        float4 xv = *(const float4*)&X[(size_t)(k0 + xk) * C1_ + cb + xc];
        __syncthreads();   // previous iteration's compute done before overwrite
        As[(ak + 0) * 132 + am] = a0.x;
        As[(ak + 1) * 132 + am] = a0.y;
        As[(ak + 2) * 132 + am] = a0.z;
        As[(ak + 3) * 132 + am] = a0.w;
        As[(ak + 4) * 132 + am] = a1.x;
        As[(ak + 5) * 132 + am] = a1.y;
        As[(ak + 6) * 132 + am] = a1.z;
        As[(ak + 7) * 132 + am] = a1.w;
        *(float4*)&Xs[xk * 64 + xc] = xv;
        __syncthreads();
#pragma unroll
        for (int kk = 0; kk < 16; ++kk) {
            float4 av0 = *(const float4*)&As[kk * 132 + ty * 8];
            float4 av1 = *(const float4*)&As[kk * 132 + ty * 8 + 4];
            float4 xv4 = *(const float4*)&Xs[kk * 64 + tx * 4];
            float a[8] = {av0.x, av0.y, av0.z, av0.w, av1.x, av1.y, av1.z, av1.w};
            float xr[4] = {xv4.x, xv4.y, xv4.z, xv4.w};
#pragma unroll
            for (int r = 0; r < 8; ++r)
#pragma unroll
                for (int c = 0; c < 4; ++c) acc[r][c] += a[r] * xr[c];
        }
    }

#pragma unroll
    for (int r = 0; r < 8; ++r) {
        int row = rb + ty * 8 + r;
        float v[4];
#pragma unroll
        for (int c = 0; c < 4; ++c) {
            v[c] = acc[r][c];
            if (bias) v[c] += bias[(tx * 4 + c) & 31];
            if (relu) v[c] = fmaxf(v[c], 0.f);
        }
        float4 o = {v[0], v[1], v[2], v[3]};
        *(float4*)&Y[(size_t)row * C1_ + cb + tx * 4] = o;
    }
}

// ---------------------------------------------------------------------------
// Kernel: spatial[bt,h] = (1/N) * sum_m relu( sum_g AG[m, bt*32+g] * w1[g,h] + b1[h] )
// grid 120, block 256 (h = tid&63, m-lane = tid>>6), loops all 1024 m. No atomics.
// ---------------------------------------------------------------------------
__global__ void k_h2mean(const float* __restrict__ AG, const float* __restrict__ w1,
                         const float* __restrict__ b1, float* __restrict__ spatial) {
    int bt = blockIdx.x, tid = threadIdx.x;
    int h = tid & 63, ml = tid >> 6;
    __shared__ float w1s[G0_ * H_];   // 2048
    __shared__ float ags[4][G0_];
    __shared__ float red[4][64];
    *(float4*)&w1s[tid * 8]     = *(const float4*)&w1[tid * 8];
    *(float4*)&w1s[tid * 8 + 4] = *(const float4*)&w1[tid * 8 + 4];
    float bh = b1[h];
    float acc = 0.f;
    for (int mc = 0; mc < 256; ++mc) {
        __syncthreads();
        if (tid < 128) {
            int rml = tid >> 5, gg = tid & 31;
            ags[rml][gg] = AG[(size_t)(mc * 4 + rml) * C1_ + bt * G0_ + gg];
        }
        __syncthreads();
        float v = bh;
#pragma unroll
        for (int g = 0; g < G0_; ++g) v += ags[ml][g] * w1s[g * H_ + h];
        acc += fmaxf(v, 0.f);
    }
    red[ml][h] = acc;
    __syncthreads();
    if (tid < 64) {
        float t = red[0][tid] + red[1][tid] + red[2][tid] + red[3][tid];
        spatial[bt * H_ + tid] = t * (1.0f / N_);
    }
}

// ---------------------------------------------------------------------------
// Kernel: temporal conv stack (only needed positions) + fusion + prediction MLP
// grid 8 (one block per batch), 64 threads (one per channel)
// conv semantics: y[o,p] = relu(b[o] + sum_{i,k} w[o,i,k] * in[i, p-(2-k)*dil])
// ---------------------------------------------------------------------------
__global__ void k_head(const float* __restrict__ spatial,
                       const float* __restrict__ cw0, const float* __restrict__ cb0,
                       const float* __restrict__ cw1, const float* __restrict__ cb1,
                       const float* __restrict__ cw2, const float* __restrict__ cb2,
                       const float* __restrict__ fw,  const float* __restrict__ fb,
                       const float* __restrict__ pw1, const float* __restrict__ pb1,
                       const float* __restrict__ pw2, const float* __restrict__ pb2,
                       float* __restrict__ out) {
    int b = blockIdx.x, o = threadIdx.x;   // 64 threads
    __shared__ float sp[15][64], c0s[15][64], c1s[15][64];
    __shared__ float lastv[64], fusedv[64], p1s[32];
    for (int t = 0; t < 15; ++t) sp[t][o] = spatial[(b * 15 + t) * 64 + o];
    __syncthreads();
    // conv0 (dil 1) at tau = 2,4,...,14
    for (int it = 0; it < 7; ++it) {
        int t = 2 + 2 * it;
        float v = cb0[o];
#pragma unroll
        for (int k = 0; k < 3; ++k) {
            const float* in = sp[t - (2 - k)];
            const float* wr = cw0 + o * 192 + k;
            for (int i = 0; i < 64; ++i) v += wr[i * 3] * in[i];
        }
        c0s[t][o] = fmaxf(v, 0.f);
    }
    __syncthreads();
    // conv1 (dil 2) at tau = 6,10,14
    for (int it = 0; it < 3; ++it) {
        int t = 6 + 4 * it;
        float v = cb1[o];
#pragma unroll
        for (int k = 0; k < 3; ++k) {
            const float* in = c0s[t - (2 - k) * 2];
            const float* wr = cw1 + o * 192 + k;
            for (int i = 0; i < 64; ++i) v += wr[i * 3] * in[i];
        }
        c1s[t][o] = fmaxf(v, 0.f);
    }
    __syncthreads();
    // conv2 (dil 4) at tau = 14
    {
        float v = cb2[o];
#pragma unroll
        for (int k = 0; k < 3; ++k) {
            const float* in = c1s[14 - (2 - k) * 4];
            const float* wr = cw2 + o * 192 + k;
            for (int i = 0; i < 64; ++i) v += wr[i * 3] * in[i];
        }
        lastv[o] = fmaxf(v, 0.f);
    }
    __syncthreads();
    // fusion: fused = relu(last @ fw + fb)
    {
        float v = fb[o];
        for (int i = 0; i < 64; ++i) v += lastv[i] * fw[i * 64 + o];
        fusedv[o] = fmaxf(v, 0.f);
    }
    __syncthreads();
    if (o < 32) {
        float v = pb1[o];
        for (int i = 0; i < 64; ++i) v += fusedv[i] * pw1[i * 32 + o];
        p1s[o] = fmaxf(v, 0.f);
    }
    __syncthreads();
    if (o == 0) {
        float v = pb2[0];
        for (int i = 0; i < 32; ++i) v += p1s[i] * pw2[i];
        out[b] = v;
    }
}

// ---------------------------------------------------------------------------
extern "C" void kernel_launch(void* const* d_in, const int* in_sizes, int n_in,
                              void* d_out, int out_size, void* d_ws, size_t ws_size,
                              hipStream_t stream) {
    (void)in_sizes; (void)n_in; (void)out_size; (void)ws_size;
    const float* x   = (const float*)d_in[0];
    const float* adj = (const float*)d_in[1];
    const float* w0  = (const float*)d_in[2];
    const float* b0  = (const float*)d_in[3];
    const float* w1  = (const float*)d_in[4];
    const float* b1  = (const float*)d_in[5];
    const float* cw0 = (const float*)d_in[6];
    const float* cb0 = (const float*)d_in[7];
    const float* cw1 = (const float*)d_in[8];
    const float* cb1 = (const float*)d_in[9];
    const float* cw2 = (const float*)d_in[10];
    const float* cb2 = (const float*)d_in[11];
    const float* fw  = (const float*)d_in[12];
    const float* fb  = (const float*)d_in[13];
    const float* pw1 = (const float*)d_in[14];
    const float* pb1 = (const float*)d_in[15];
    const float* pw2 = (const float*)d_in[16];
    const float* pb2 = (const float*)d_in[17];
    float* outp = (float*)d_out;

    // Workspace layout (floats): all offsets 16B-aligned.
    float* ws      = (float*)d_ws;
    float* dis     = ws;                              // 1024
    float* an      = ws + 1024;                       // 1024*1024
    float* xw0     = an + (size_t)N_ * N_;            // 1024*3840  (reused as AG)
    float* h1      = xw0 + (size_t)N_ * C1_;          // 1024*3840
    float* spatial = h1 + (size_t)N_ * C1_;           // 120*64
    float* ag      = xw0;                             // alias: XW0 is dead after GEMM1

    k_deg<<<N_, 256, 0, stream>>>(adj, dis);
    k_an<<<(N_ * N_) / 256, 256, 0, stream>>>(adj, dis, an);
    k_xw0<<<dim3(N_ / 8, BT_), 256, 0, stream>>>(x, w0, xw0);
    k_gemm<<<dim3(C1_ / 64, N_ / 128), 256, 0, stream>>>(an, xw0, h1, b0, 1);
    k_gemm<<<dim3(C1_ / 64, N_ / 128), 256, 0, stream>>>(an, h1, ag, nullptr, 0);
    k_h2mean<<<BT_, 256, 0, stream>>>(ag, w1, b1, spatial);
    k_head<<<B_, 64, 0, stream>>>(spatial, cw0, cb0, cw1, cb1, cw2, cb2,
                                  fw, fb, pw1, pb1, pw2, pb2, outp);
}

// Round 2
// 811.425 us; speedup vs baseline: 1.3267x; 1.3267x over previous
//
#include <hip/hip_runtime.h>
#include <hip/hip_bf16.h>

// Problem constants
#define B_   8
#define S_   512
#define N_   1024
#define F_   32
#define H_   64
#define G0_  32
#define T_   15          // trailing time steps needed (receptive field of last pos)
#define BT_  (B_ * T_)   // 120
#define C1_  (BT_ * G0_) // 3840 rows of the transposed activation matrices

typedef __bf16 bfx8 __attribute__((ext_vector_type(8)));
typedef __bf16 bfx4 __attribute__((ext_vector_type(4)));
typedef float  f32x4 __attribute__((ext_vector_type(4)));

// async global->LDS, 16B per lane; lds ptr must be wave-uniform (lane*16 implicit)
__device__ __forceinline__ void async16(void* l, const void* g) {
    __builtin_amdgcn_global_load_lds(
        (__attribute__((address_space(1))) const void*)g,
        (__attribute__((address_space(3))) void*)l, 16, 0, 0);
}

// ---------------------------------------------------------------------------
// dis[r] = rsqrt(1 + sum_n adj[r,n])
// ---------------------------------------------------------------------------
__global__ void k_deg(const float* __restrict__ adj, float* __restrict__ dis) {
    int r = blockIdx.x;
    int tid = threadIdx.x;
    const float* row = adj + (size_t)r * N_;
    float p = 0.f;
    for (int n = tid; n < N_; n += 256) p += row[n];
    __shared__ float red[256];
    red[tid] = p;
    __syncthreads();
    for (int s = 128; s > 0; s >>= 1) {
        if (tid < s) red[tid] += red[tid + s];
        __syncthreads();
    }
    if (tid == 0) {
        float deg = red[0] + 1.0f;
        dis[r] = (deg > 0.f) ? rsqrtf(deg) : 0.f;
    }
}

// ---------------------------------------------------------------------------
// AN[m,n] = dis[m]*(adj[m,n] + (m==n))*dis[n], emitted in bf16 (MFMA A-operand)
// ---------------------------------------------------------------------------
__global__ void k_an(const float* __restrict__ adj, const float* __restrict__ dis,
                     __bf16* __restrict__ an) {
    int idx = (blockIdx.x * 256 + threadIdx.x) * 4;   // grid 1024 -> 1M elems
    int m = idx >> 10, n0 = idx & 1023;
    float dm = dis[m];
    float4 a = *(const float4*)&adj[idx];
    float v[4] = {a.x, a.y, a.z, a.w};
    bfx4 o;
#pragma unroll
    for (int j = 0; j < 4; ++j) {
        float vv = v[j] + ((n0 + j) == m ? 1.0f : 0.0f);
        o[j] = (__bf16)(dm * vv * dis[n0 + j]);
    }
    *(bfx4*)&an[idx] = o;
}

// ---------------------------------------------------------------------------
// XW0T[c=bt*32+g][n] = x[b,s(tau),n,:] @ w0[:,g]   (bf16, n contiguous)
// grid (32, 120), block 256
// ---------------------------------------------------------------------------
__global__ void k_xw0(const float* __restrict__ x, const float* __restrict__ w0,
                      __bf16* __restrict__ xw0t) {
    int bt = blockIdx.y, n0 = blockIdx.x * 32, tid = threadIdx.x;
    int b = bt / T_, tau = bt % T_, s = S_ - T_ + tau;
    __shared__ float xs[32][33];    // [n][f], padded
    __shared__ float w0s[32 * 32];  // [f][g]
    const float* xp = x + ((size_t)((b * S_ + s) * N_ + n0)) * F_;
    {
        int r = tid >> 3, c4 = (tid & 7) * 4;
        *(float4*)&xs[r][c4] = *(const float4*)&xp[r * 32 + c4];
        *(float4*)&w0s[tid * 4] = *(const float4*)&w0[tid * 4];
    }
    __syncthreads();
    int g = tid >> 3, nb = (tid & 7) * 4;
    float a0 = 0.f, a1 = 0.f, a2 = 0.f, a3 = 0.f;
#pragma unroll
    for (int f = 0; f < 32; ++f) {
        float wv = w0s[f * 32 + g];
        a0 += xs[nb + 0][f] * wv;
        a1 += xs[nb + 1][f] * wv;
        a2 += xs[nb + 2][f] * wv;
        a3 += xs[nb + 3][f] * wv;
    }
    bfx4 o;
    o[0] = (__bf16)a0; o[1] = (__bf16)a1; o[2] = (__bf16)a2; o[3] = (__bf16)a3;
    *(bfx4*)&xw0t[(size_t)(bt * 32 + g) * N_ + n0 + nb] = o;
}

// ---------------------------------------------------------------------------
// MFMA GEMM: D[m][c] = sum_k A[m][k] * Bm[c][k]   (A: 1024xK row-major bf16,
// Bm: 3840xK row-major bf16, K=1024). Output written TRANSPOSED: C_T[c][m].
// MODE 1: relu(D + bias[c%32]) -> bf16 C_T.   MODE 0: fp32 C_T.
// Tile 128(m) x 128(c), BK=32, 256 threads (4 waves, each 64x64 via 4x4 MFMAs).
// grid (3840/128=30, 1024/128=8)
// ---------------------------------------------------------------------------
template <int MODE>
__global__ __launch_bounds__(256) void k_mm(const __bf16* __restrict__ A,
                                            const __bf16* __restrict__ Bm,
                                            void* __restrict__ Cv,
                                            const float* __restrict__ bias) {
    __shared__ __bf16 As[128 * 32];
    __shared__ __bf16 Bs[128 * 32];
    int tid = threadIdx.x;
    int lane = tid & 63, wv = tid >> 6;
    int rb = blockIdx.y * 128;            // m-block (A rows)
    int cb = blockIdx.x * 128;            // c-block (Bm rows)
    int wr = (wv >> 1) * 64, wc = (wv & 1) * 64;

    f32x4 acc[4][4] = {};

    // staging: per instruction a wave moves 16 rows x 32 bf16 (1 KB)
    int srow = lane >> 2;                 // 0..15
    int scol = (lane & 3) * 8;            // bf16 offset within 32-elem row chunk
    const __bf16* gA0 = A  + (size_t)(rb + wv * 16 + srow) * 1024 + scol;
    const __bf16* gA1 = gA0 + (size_t)64 * 1024;
    const __bf16* gB0 = Bm + (size_t)(cb + wv * 16 + srow) * 1024 + scol;
    const __bf16* gB1 = gB0 + (size_t)64 * 1024;
    __bf16* lA0 = As + wv * 512;          // wave-uniform LDS bases
    __bf16* lA1 = As + 2048 + wv * 512;
    __bf16* lB0 = Bs + wv * 512;
    __bf16* lB1 = Bs + 2048 + wv * 512;

    const int c16 = lane & 15;
    const int qa  = (lane >> 4) * 8;

    for (int k0 = 0; k0 < 1024; k0 += 32) {
        async16(lA0, gA0 + k0);
        async16(lA1, gA1 + k0);
        async16(lB0, gB0 + k0);
        async16(lB1, gB1 + k0);
        __syncthreads();                  // drains vmcnt before barrier
        bfx8 af[4], bfv[4];
#pragma unroll
        for (int r = 0; r < 4; ++r)
            af[r] = *(const bfx8*)&As[(wr + 16 * r + c16) * 32 + qa];
#pragma unroll
        for (int c = 0; c < 4; ++c)
            bfv[c] = *(const bfx8*)&Bs[(wc + 16 * c + c16) * 32 + qa];
#pragma unroll
        for (int r = 0; r < 4; ++r)
#pragma unroll
            for (int c = 0; c < 4; ++c)
                acc[r][c] = __builtin_amdgcn_mfma_f32_16x16x32_bf16(
                    af[r], bfv[c], acc[r][c], 0, 0, 0);
        __syncthreads();                  // LDS reusable next iter
    }

    // Epilogue: lane holds D[m_local = quad*4+reg][c_local = lane&15] per tile.
    int quad = lane >> 4;
    if (MODE == 1) {
        __bf16* C = (__bf16*)Cv;
        float be = bias[c16], bo = bias[c16 + 16];
#pragma unroll
        for (int cj = 0; cj < 4; ++cj) {
            size_t cc = (size_t)(cb + wc + 16 * cj + c16);
            float bg = (cj & 1) ? bo : be;
#pragma unroll
            for (int r = 0; r < 4; ++r) {
                int m4 = rb + wr + 16 * r + quad * 4;
                f32x4 v = acc[r][cj];
                bfx4 o;
#pragma unroll
                for (int j = 0; j < 4; ++j) o[j] = (__bf16)fmaxf(v[j] + bg, 0.f);
                *(bfx4*)&C[cc * 1024 + m4] = o;
            }
        }
    } else {
        float* C = (float*)Cv;
#pragma unroll
        for (int cj = 0; cj < 4; ++cj) {
            size_t cc = (size_t)(cb + wc + 16 * cj + c16);
#pragma unroll
            for (int r = 0; r < 4; ++r) {
                int m4 = rb + wr + 16 * r + quad * 4;
                *(f32x4*)&C[cc * 1024 + m4] = acc[r][cj];
            }
        }
    }
}

// ---------------------------------------------------------------------------
// spatial[bt,h] = (1/N) * sum_m relu( sum_g AGT[bt*32+g][m]*w1[g,h] + b1[h] )
// AGT is fp32 [3840][1024]. grid 120, block 256.
// ---------------------------------------------------------------------------
__global__ void k_h2mean(const float* __restrict__ AGT, const float* __restrict__ w1,
                         const float* __restrict__ b1, float* __restrict__ spatial) {
    int bt = blockIdx.x, tid = threadIdx.x;
    int h = tid & 63, sub = tid >> 6;
    __shared__ float w1s[G0_ * H_];   // 2048
    __shared__ float ags[32][64];     // [g][m-chunk]
    __shared__ float red[4][64];
    *(float4*)&w1s[tid * 8]     = *(const float4*)&w1[tid * 8];
    *(float4*)&w1s[tid * 8 + 4] = *(const float4*)&w1[tid * 8 + 4];
    float bh = b1[h];
    float acc = 0.f;
    int sg = tid >> 3, sm = (tid & 7) * 8;
    for (int mc = 0; mc < 1024; mc += 64) {
        __syncthreads();
        const float* src = AGT + (size_t)(bt * 32 + sg) * 1024 + mc + sm;
        *(float4*)&ags[sg][sm]     = *(const float4*)src;
        *(float4*)&ags[sg][sm + 4] = *(const float4*)(src + 4);
        __syncthreads();
#pragma unroll 4
        for (int j = 0; j < 16; ++j) {
            int m = sub * 16 + j;
            float v = bh;
#pragma unroll
            for (int g = 0; g < 32; ++g) v += ags[g][m] * w1s[g * 64 + h];
            acc += fmaxf(v, 0.f);
        }
    }
    red[sub][h] = acc;
    __syncthreads();
    if (tid < 64) {
        float t = red[0][tid] + red[1][tid] + red[2][tid] + red[3][tid];
        spatial[bt * 64 + tid] = t * (1.0f / N_);
    }
}

// ---------------------------------------------------------------------------
// temporal conv stack (needed positions only) + fusion + prediction MLP
// grid 8, block 64
// ---------------------------------------------------------------------------
__global__ void k_head(const float* __restrict__ spatial,
                       const float* __restrict__ cw0, const float* __restrict__ cb0,
                       const float* __restrict__ cw1, const float* __restrict__ cb1,
                       const float* __restrict__ cw2, const float* __restrict__ cb2,
                       const float* __restrict__ fw,  const float* __restrict__ fb,
                       const float* __restrict__ pw1, const float* __restrict__ pb1,
                       const float* __restrict__ pw2, const float* __restrict__ pb2,
                       float* __restrict__ out) {
    int b = blockIdx.x, o = threadIdx.x;
    __shared__ float sp[15][64], c0s[15][64], c1s[15][64];
    __shared__ float lastv[64], fusedv[64], p1s[32];
    for (int t = 0; t < 15; ++t) sp[t][o] = spatial[(b * 15 + t) * 64 + o];
    __syncthreads();
    for (int it = 0; it < 7; ++it) {          // conv0 dil1 at tau=2,4,..,14
        int t = 2 + 2 * it;
        float v = cb0[o];
#pragma unroll
        for (int k = 0; k < 3; ++k) {
            const float* in = sp[t - (2 - k)];
            const float* wr = cw0 + o * 192 + k;
            for (int i = 0; i < 64; ++i) v += wr[i * 3] * in[i];
        }
        c0s[t][o] = fmaxf(v, 0.f);
    }
    __syncthreads();
    for (int it = 0; it < 3; ++it) {          // conv1 dil2 at tau=6,10,14
        int t = 6 + 4 * it;
        float v = cb1[o];
#pragma unroll
        for (int k = 0; k < 3; ++k) {
            const float* in = c0s[t - (2 - k) * 2];
            const float* wr = cw1 + o * 192 + k;
            for (int i = 0; i < 64; ++i) v += wr[i * 3] * in[i];
        }
        c1s[t][o] = fmaxf(v, 0.f);
    }
    __syncthreads();
    {                                          // conv2 dil4 at tau=14
        float v = cb2[o];
#pragma unroll
        for (int k = 0; k < 3; ++k) {
            const float* in = c1s[14 - (2 - k) * 4];
            const float* wr = cw2 + o * 192 + k;
            for (int i = 0; i < 64; ++i) v += wr[i * 3] * in[i];
        }
        lastv[o] = fmaxf(v, 0.f);
    }
    __syncthreads();
    {
        float v = fb[o];
        for (int i = 0; i < 64; ++i) v += lastv[i] * fw[i * 64 + o];
        fusedv[o] = fmaxf(v, 0.f);
    }
    __syncthreads();
    if (o < 32) {
        float v = pb1[o];
        for (int i = 0; i < 64; ++i) v += fusedv[i] * pw1[i * 32 + o];
        p1s[o] = fmaxf(v, 0.f);
    }
    __syncthreads();
    if (o == 0) {
        float v = pb2[0];
        for (int i = 0; i < 32; ++i) v += p1s[i] * pw2[i];
        out[b] = v;
    }
}

// ---------------------------------------------------------------------------
extern "C" void kernel_launch(void* const* d_in, const int* in_sizes, int n_in,
                              void* d_out, int out_size, void* d_ws, size_t ws_size,
                              hipStream_t stream) {
    (void)in_sizes; (void)n_in; (void)out_size; (void)ws_size;
    const float* x   = (const float*)d_in[0];
    const float* adj = (const float*)d_in[1];
    const float* w0  = (const float*)d_in[2];
    const float* b0  = (const float*)d_in[3];
    const float* w1  = (const float*)d_in[4];
    const float* b1  = (const float*)d_in[5];
    const float* cw0 = (const float*)d_in[6];
    const float* cb0 = (const float*)d_in[7];
    const float* cw1 = (const float*)d_in[8];
    const float* cb1 = (const float*)d_in[9];
    const float* cw2 = (const float*)d_in[10];
    const float* cb2 = (const float*)d_in[11];
    const float* fw  = (const float*)d_in[12];
    const float* fb  = (const float*)d_in[13];
    const float* pw1 = (const float*)d_in[14];
    const float* pb1 = (const float*)d_in[15];
    const float* pw2 = (const float*)d_in[16];
    const float* pb2 = (const float*)d_in[17];
    float* outp = (float*)d_out;

    // Workspace layout (bytes, all 16B-aligned)
    char* w = (char*)d_ws;
    float*  dis     = (float*)(w);                       //   4 KB
    __bf16* an      = (__bf16*)(w + 4096);               //   2 MB
    __bf16* xw0t    = (__bf16*)(w + 4096 + 2097152);     // 7.5 MB (3840x1024 bf16)
    __bf16* h1t     = (__bf16*)(w + 4096 + 2097152 + 7864320);
    float*  agt     = (float*) (w + 4096 + 2097152 + 2 * 7864320);   // 15 MB fp32
    float*  spatial = (float*) (w + 4096 + 2097152 + 2 * 7864320 + 15728640);

    k_deg<<<N_, 256, 0, stream>>>(adj, dis);
    k_an<<<(N_ * N_) / 1024, 256, 0, stream>>>(adj, dis, an);
    k_xw0<<<dim3(N_ / 32, BT_), 256, 0, stream>>>(x, w0, xw0t);
    k_mm<1><<<dim3(C1_ / 128, N_ / 128), 256, 0, stream>>>(an, xw0t, (void*)h1t, b0);
    k_mm<0><<<dim3(C1_ / 128, N_ / 128), 256, 0, stream>>>(an, h1t, (void*)agt, nullptr);
    k_h2mean<<<BT_, 256, 0, stream>>>(agt, w1, b1, spatial);
    k_head<<<B_, 64, 0, stream>>>(spatial, cw0, cb0, cw1, cb1, cw2, cb2,
                                  fw, fb, pw1, pb1, pw2, pb2, outp);
}

// Round 3
// 750.594 us; speedup vs baseline: 1.4343x; 1.0810x over previous
//
#include <hip/hip_runtime.h>
#include <hip/hip_bf16.h>

// Problem constants
#define B_   8
#define S_   512
#define N_   1024
#define F_   32
#define H_   64
#define G0_  32
#define T_   15          // trailing time steps needed (receptive field of last pos)
#define BT_  (B_ * T_)   // 120
#define C1_  (BT_ * G0_) // 3840 rows of the transposed activation matrices

typedef __bf16 bfx8 __attribute__((ext_vector_type(8)));
typedef __bf16 bfx4 __attribute__((ext_vector_type(4)));
typedef float  f32x4 __attribute__((ext_vector_type(4)));

// async global->LDS, 16B per lane; lds ptr must be wave-uniform (lane*16 implicit)
__device__ __forceinline__ void async16(void* l, const void* g) {
    __builtin_amdgcn_global_load_lds(
        (__attribute__((address_space(1))) const void*)g,
        (__attribute__((address_space(3))) void*)l, 16, 0, 0);
}

// ---------------------------------------------------------------------------
// dis[r] = rsqrt(1 + sum_n adj[r,n])
// ---------------------------------------------------------------------------
__global__ void k_deg(const float* __restrict__ adj, float* __restrict__ dis) {
    int r = blockIdx.x;
    int tid = threadIdx.x;
    const float* row = adj + (size_t)r * N_;
    float p = 0.f;
    for (int n = tid; n < N_; n += 256) p += row[n];
    __shared__ float red[256];
    red[tid] = p;
    __syncthreads();
    for (int s = 128; s > 0; s >>= 1) {
        if (tid < s) red[tid] += red[tid + s];
        __syncthreads();
    }
    if (tid == 0) {
        float deg = red[0] + 1.0f;
        dis[r] = (deg > 0.f) ? rsqrtf(deg) : 0.f;
    }
}

// ---------------------------------------------------------------------------
// AN[m,n] = dis[m]*(adj[m,n] + (m==n))*dis[n], emitted in bf16 (MFMA A-operand)
// ---------------------------------------------------------------------------
__global__ void k_an(const float* __restrict__ adj, const float* __restrict__ dis,
                     __bf16* __restrict__ an) {
    int idx = (blockIdx.x * 256 + threadIdx.x) * 4;   // grid 1024 -> 1M elems
    int m = idx >> 10, n0 = idx & 1023;
    float dm = dis[m];
    float4 a = *(const float4*)&adj[idx];
    float v[4] = {a.x, a.y, a.z, a.w};
    bfx4 o;
#pragma unroll
    for (int j = 0; j < 4; ++j) {
        float vv = v[j] + ((n0 + j) == m ? 1.0f : 0.0f);
        o[j] = (__bf16)(dm * vv * dis[n0 + j]);
    }
    *(bfx4*)&an[idx] = o;
}

// ---------------------------------------------------------------------------
// XW0T[c=bt*32+g][n] = x[b,s(tau),n,:] @ w0[:,g]   (bf16, n contiguous)
// grid (32, 120), block 256
// ---------------------------------------------------------------------------
__global__ void k_xw0(const float* __restrict__ x, const float* __restrict__ w0,
                      __bf16* __restrict__ xw0t) {
    int bt = blockIdx.y, n0 = blockIdx.x * 32, tid = threadIdx.x;
    int b = bt / T_, tau = bt % T_, s = S_ - T_ + tau;
    __shared__ float xs[32][33];    // [n][f], padded
    __shared__ float w0s[32 * 32];  // [f][g]
    const float* xp = x + ((size_t)((b * S_ + s) * N_ + n0)) * F_;
    {
        int r = tid >> 3, c4 = (tid & 7) * 4;
        *(float4*)&xs[r][c4] = *(const float4*)&xp[r * 32 + c4];
        *(float4*)&w0s[tid * 4] = *(const float4*)&w0[tid * 4];
    }
    __syncthreads();
    int g = tid >> 3, nb = (tid & 7) * 4;
    float a0 = 0.f, a1 = 0.f, a2 = 0.f, a3 = 0.f;
#pragma unroll
    for (int f = 0; f < 32; ++f) {
        float wv = w0s[f * 32 + g];
        a0 += xs[nb + 0][f] * wv;
        a1 += xs[nb + 1][f] * wv;
        a2 += xs[nb + 2][f] * wv;
        a3 += xs[nb + 3][f] * wv;
    }
    bfx4 o;
    o[0] = (__bf16)a0; o[1] = (__bf16)a1; o[2] = (__bf16)a2; o[3] = (__bf16)a3;
    *(bfx4*)&xw0t[(size_t)(bt * 32 + g) * N_ + n0 + nb] = o;
}

// ---------------------------------------------------------------------------
// MFMA GEMM: D[m][c] = sum_k A[m][k] * Bm[c][k]   (A: 1024xK row-major bf16,
// Bm: 3840xK row-major bf16, K=1024). Output written TRANSPOSED: C_T[c][m].
// MODE 1: relu(D + bias[c%32]) -> bf16 C_T.   MODE 0: fp32 C_T.
// Tile 128(m) x 128(c), BK=32, 256 threads (4 waves, each 64x64 via 4x4 MFMAs).
// grid (3840/128=30, 1024/128=8)
// ---------------------------------------------------------------------------
template <int MODE>
__global__ __launch_bounds__(256) void k_mm(const __bf16* __restrict__ A,
                                            const __bf16* __restrict__ Bm,
                                            void* __restrict__ Cv,
                                            const float* __restrict__ bias) {
    __shared__ __bf16 As[128 * 32];
    __shared__ __bf16 Bs[128 * 32];
    int tid = threadIdx.x;
    int lane = tid & 63, wv = tid >> 6;
    int rb = blockIdx.y * 128;            // m-block (A rows)
    int cb = blockIdx.x * 128;            // c-block (Bm rows)
    int wr = (wv >> 1) * 64, wc = (wv & 1) * 64;

    f32x4 acc[4][4] = {};

    // staging: per instruction a wave moves 16 rows x 32 bf16 (1 KB)
    int srow = lane >> 2;                 // 0..15
    int scol = (lane & 3) * 8;            // bf16 offset within 32-elem row chunk
    const __bf16* gA0 = A  + (size_t)(rb + wv * 16 + srow) * 1024 + scol;
    const __bf16* gA1 = gA0 + (size_t)64 * 1024;
    const __bf16* gB0 = Bm + (size_t)(cb + wv * 16 + srow) * 1024 + scol;
    const __bf16* gB1 = gB0 + (size_t)64 * 1024;
    __bf16* lA0 = As + wv * 512;          // wave-uniform LDS bases
    __bf16* lA1 = As + 2048 + wv * 512;
    __bf16* lB0 = Bs + wv * 512;
    __bf16* lB1 = Bs + 2048 + wv * 512;

    const int c16 = lane & 15;
    const int qa  = (lane >> 4) * 8;

    for (int k0 = 0; k0 < 1024; k0 += 32) {
        async16(lA0, gA0 + k0);
        async16(lA1, gA1 + k0);
        async16(lB0, gB0 + k0);
        async16(lB1, gB1 + k0);
        __syncthreads();                  // drains vmcnt before barrier
        bfx8 af[4], bfv[4];
#pragma unroll
        for (int r = 0; r < 4; ++r)
            af[r] = *(const bfx8*)&As[(wr + 16 * r + c16) * 32 + qa];
#pragma unroll
        for (int c = 0; c < 4; ++c)
            bfv[c] = *(const bfx8*)&Bs[(wc + 16 * c + c16) * 32 + qa];
#pragma unroll
        for (int r = 0; r < 4; ++r)
#pragma unroll
            for (int c = 0; c < 4; ++c)
                acc[r][c] = __builtin_amdgcn_mfma_f32_16x16x32_bf16(
                    af[r], bfv[c], acc[r][c], 0, 0, 0);
        __syncthreads();                  // LDS reusable next iter
    }

    // Epilogue: lane holds D[m_local = quad*4+reg][c_local = lane&15] per tile.
    int quad = lane >> 4;
    if (MODE == 1) {
        __bf16* C = (__bf16*)Cv;
        float be = bias[c16], bo = bias[c16 + 16];
#pragma unroll
        for (int cj = 0; cj < 4; ++cj) {
            size_t cc = (size_t)(cb + wc + 16 * cj + c16);
            float bg = (cj & 1) ? bo : be;
#pragma unroll
            for (int r = 0; r < 4; ++r) {
                int m4 = rb + wr + 16 * r + quad * 4;
                f32x4 v = acc[r][cj];
                bfx4 o;
#pragma unroll
                for (int j = 0; j < 4; ++j) o[j] = (__bf16)fmaxf(v[j] + bg, 0.f);
                *(bfx4*)&C[cc * 1024 + m4] = o;
            }
        }
    } else {
        float* C = (float*)Cv;
#pragma unroll
        for (int cj = 0; cj < 4; ++cj) {
            size_t cc = (size_t)(cb + wc + 16 * cj + c16);
#pragma unroll
            for (int r = 0; r < 4; ++r) {
                int m4 = rb + wr + 16 * r + quad * 4;
                *(f32x4*)&C[cc * 1024 + m4] = acc[r][cj];
            }
        }
    }
}

// ---------------------------------------------------------------------------
// spatial[bt,h] = (1/N) * sum_m relu( sum_g AGT[bt*32+g][m]*w1[g,h] + b1[h] )
// AGT is fp32 [3840][1024]. grid 120, block 256.
// Thread owns h (w1 column in 32 registers) + a 256-wide m stripe; AG values
// are wave-uniform float4 loads (scalarizable) — no LDS in the hot loop.
// ---------------------------------------------------------------------------
__global__ __launch_bounds__(256) void k_h2mean(const float* __restrict__ AGT,
                                                const float* __restrict__ w1,
                                                const float* __restrict__ b1,
                                                float* __restrict__ spatial) {
    int bt = blockIdx.x, tid = threadIdx.x;
    int h = tid & 63, sub = tid >> 6;
    float w1r[32];
#pragma unroll
    for (int g = 0; g < 32; ++g) w1r[g] = w1[g * 64 + h];
    float bh = b1[h];
    float acc = 0.f;
    const float* base = AGT + (size_t)(bt * 32) * 1024 + sub * 256;
    for (int mq = 0; mq < 64; ++mq) {
        float v0 = bh, v1 = bh, v2 = bh, v3 = bh;
#pragma unroll
        for (int g = 0; g < 32; ++g) {
            float4 a = *(const float4*)(base + (size_t)g * 1024 + mq * 4);
            v0 += a.x * w1r[g];
            v1 += a.y * w1r[g];
            v2 += a.z * w1r[g];
            v3 += a.w * w1r[g];
        }
        acc += fmaxf(v0, 0.f) + fmaxf(v1, 0.f) + fmaxf(v2, 0.f) + fmaxf(v3, 0.f);
    }
    __shared__ float red[4][64];
    red[sub][h] = acc;
    __syncthreads();
    if (tid < 64) {
        float t = red[0][tid] + red[1][tid] + red[2][tid] + red[3][tid];
        spatial[bt * 64 + tid] = t * (1.0f / N_);
    }
}

// ---------------------------------------------------------------------------
// temporal conv stack (needed positions only) + fusion + prediction MLP
// grid 8 (one block per batch), 256 threads. Conv weights staged to LDS in
// [k][i][o] layout, 65-float row stride (the natural [o][i][k] read has
// stride 192 == 0 mod 32 -> 64-way bank conflict).
// ---------------------------------------------------------------------------
__global__ __launch_bounds__(256) void k_head(const float* __restrict__ spatial,
                       const float* __restrict__ cw0, const float* __restrict__ cb0,
                       const float* __restrict__ cw1, const float* __restrict__ cb1,
                       const float* __restrict__ cw2, const float* __restrict__ cb2,
                       const float* __restrict__ fw,  const float* __restrict__ fb,
                       const float* __restrict__ pw1, const float* __restrict__ pb1,
                       const float* __restrict__ pw2, const float* __restrict__ pb2,
                       float* __restrict__ out) {
    int b = blockIdx.x, tid = threadIdx.x;
    int o = tid & 63, ti = tid >> 6;
    __shared__ float wbuf[3 * 64 * 65];            // [k][i][o], padded (48.75 KB)
    __shared__ float sp[15][64], c0s[15][64], c1s[15][64];
    __shared__ float lastv[64], fusedv[64], p1s[32];

    for (int j = tid; j < 15 * 64; j += 256) ((float*)sp)[j] = spatial[b * 960 + j];
    for (int j = tid; j < 12288; j += 256) {       // cw0 -> [k][i][o]
        int oo = j / 192, r = j % 192, ii = r / 3, kk = r % 3;
        wbuf[kk * 4160 + ii * 65 + oo] = cw0[j];
    }
    __syncthreads();
    // conv0 (dil 1) at tau = 2,4,...,14 (same FMA order as verified scalar ver.)
    for (int t4 = ti; t4 < 7; t4 += 4) {
        int t = 2 + 2 * t4;
        float v = cb0[o];
#pragma unroll
        for (int k = 0; k < 3; ++k) {
            const float* in = sp[t - 2 + k];
            const float* wk = &wbuf[k * 4160];
#pragma unroll
            for (int i = 0; i < 64; ++i) v += wk[i * 65 + o] * in[i];
        }
        c0s[t][o] = fmaxf(v, 0.f);
    }
    __syncthreads();
    for (int j = tid; j < 12288; j += 256) {       // cw1 -> [k][i][o]
        int oo = j / 192, r = j % 192, ii = r / 3, kk = r % 3;
        wbuf[kk * 4160 + ii * 65 + oo] = cw1[j];
    }
    __syncthreads();
    // conv1 (dil 2) at tau = 6,10,14
    if (ti < 3) {
        int t = 6 + 4 * ti;
        float v = cb1[o];
#pragma unroll
        for (int k = 0; k < 3; ++k) {
            const float* in = c0s[t - (2 - k) * 2];
            const float* wk = &wbuf[k * 4160];
#pragma unroll
            for (int i = 0; i < 64; ++i) v += wk[i * 65 + o] * in[i];
        }
        c1s[t][o] = fmaxf(v, 0.f);
    }
    __syncthreads();
    for (int j = tid; j < 12288; j += 256) {       // cw2 -> [k][i][o]
        int oo = j / 192, r = j % 192, ii = r / 3, kk = r % 3;
        wbuf[kk * 4160 + ii * 65 + oo] = cw2[j];
    }
    __syncthreads();
    // conv2 (dil 4) at tau = 14
    if (ti == 0) {
        float v = cb2[o];
#pragma unroll
        for (int k = 0; k < 3; ++k) {
            const float* in = c1s[14 - (2 - k) * 4];
            const float* wk = &wbuf[k * 4160];
#pragma unroll
            for (int i = 0; i < 64; ++i) v += wk[i * 65 + o] * in[i];
        }
        lastv[o] = fmaxf(v, 0.f);
    }
    __syncthreads();
    if (ti == 0) {                                  // fusion
        float v = fb[o];
#pragma unroll
        for (int i = 0; i < 64; ++i) v += lastv[i] * fw[i * 64 + o];
        fusedv[o] = fmaxf(v, 0.f);
    }
    __syncthreads();
    if (tid < 32) {                                 // pred layer 1
        float v = pb1[tid];
#pragma unroll
        for (int i = 0; i < 64; ++i) v += fusedv[i] * pw1[i * 32 + tid];
        p1s[tid] = fmaxf(v, 0.f);
    }
    __syncthreads();
    if (tid == 0) {                                 // pred layer 2
        float v = pb2[0];
#pragma unroll
        for (int i = 0; i < 32; ++i) v += p1s[i] * pw2[i];
        out[b] = v;
    }
}

// ---------------------------------------------------------------------------
extern "C" void kernel_launch(void* const* d_in, const int* in_sizes, int n_in,
                              void* d_out, int out_size, void* d_ws, size_t ws_size,
                              hipStream_t stream) {
    (void)in_sizes; (void)n_in; (void)out_size; (void)ws_size;
    const float* x   = (const float*)d_in[0];
    const float* adj = (const float*)d_in[1];
    const float* w0  = (const float*)d_in[2];
    const float* b0  = (const float*)d_in[3];
    const float* w1  = (const float*)d_in[4];
    const float* b1  = (const float*)d_in[5];
    const float* cw0 = (const float*)d_in[6];
    const float* cb0 = (const float*)d_in[7];
    const float* cw1 = (const float*)d_in[8];
    const float* cb1 = (const float*)d_in[9];
    const float* cw2 = (const float*)d_in[10];
    const float* cb2 = (const float*)d_in[11];
    const float* fw  = (const float*)d_in[12];
    const float* fb  = (const float*)d_in[13];
    const float* pw1 = (const float*)d_in[14];
    const float* pb1 = (const float*)d_in[15];
    const float* pw2 = (const float*)d_in[16];
    const float* pb2 = (const float*)d_in[17];
    float* outp = (float*)d_out;

    // Workspace layout (bytes, all 16B-aligned)
    char* w = (char*)d_ws;
    float*  dis     = (float*)(w);                       //   4 KB
    __bf16* an      = (__bf16*)(w + 4096);               //   2 MB
    __bf16* xw0t    = (__bf16*)(w + 4096 + 2097152);     // 7.5 MB (3840x1024 bf16)
    __bf16* h1t     = (__bf16*)(w + 4096 + 2097152 + 7864320);
    float*  agt     = (float*) (w + 4096 + 2097152 + 2 * 7864320);   // 15 MB fp32
    float*  spatial = (float*) (w + 4096 + 2097152 + 2 * 7864320 + 15728640);

    k_deg<<<N_, 256, 0, stream>>>(adj, dis);
    k_an<<<(N_ * N_) / 1024, 256, 0, stream>>>(adj, dis, an);
    k_xw0<<<dim3(N_ / 32, BT_), 256, 0, stream>>>(x, w0, xw0t);
    k_mm<1><<<dim3(C1_ / 128, N_ / 128), 256, 0, stream>>>(an, xw0t, (void*)h1t, b0);
    k_mm<0><<<dim3(C1_ / 128, N_ / 128), 256, 0, stream>>>(an, h1t, (void*)agt, nullptr);
    k_h2mean<<<BT_, 256, 0, stream>>>(agt, w1, b1, spatial);
    k_head<<<B_, 256, 0, stream>>>(spatial, cw0, cb0, cw1, cb1, cw2, cb2,
                                   fw, fb, pw1, pb1, pw2, pb2, outp);
}